// Round 1
// baseline (80.698 us; speedup 1.0000x reference)
//
#include <hip/hip_runtime.h>

// Problem: out[b][j] = table_bits[idx(b)][j], j=0..63, float32 0.0/1.0 pulses.
// idx(b) = sum_k (idx_bits[b][k] > 0) << (5-k)   (MSB-first mux tree).
// Memory-bound: 6 MiB idx read + 64 MiB out write. Target ~6.3 TB/s HBM ceiling.

#define B_PER_BLOCK 64   // batch elements per block: 64 rows x 64 floats = 16 KB out/block

__global__ __launch_bounds__(256) void
spike_lut_kernel(const float* __restrict__ table,      // [64 entries][64 bits]
                 const int* __restrict__ idx_bits,     // [batch][6]
                 float4* __restrict__ out4,            // [batch][16] float4
                 int batch) {
    __shared__ float4 s_table[64 * 16];   // 16 KB: full table, float4-granular
    __shared__ int    s_idx[B_PER_BLOCK];

    const int tid = threadIdx.x;
    const int b0  = blockIdx.x * B_PER_BLOCK;

    // Stage table into LDS: 1024 float4s across 256 threads (coalesced dwordx4).
    const float4* t4 = (const float4*)table;
    #pragma unroll
    for (int r = 0; r < 4; ++r) {
        s_table[r * 256 + tid] = t4[r * 256 + tid];
    }

    // One thread per batch element computes its 6-bit index.
    if (tid < B_PER_BLOCK) {
        const int b = b0 + tid;
        int idx = 0;
        if (b < batch) {
            const int* p = idx_bits + (long)b * 6;
            #pragma unroll
            for (int k = 0; k < 6; ++k) {
                idx = (idx << 1) | (p[k] > 0 ? 1 : 0);   // MSB first: k=0 has weight 32
            }
        }
        s_idx[tid] = idx;
    }
    __syncthreads();

    // Emit 64 rows x 16 float4 = 1024 float4 per block; consecutive threads
    // write consecutive 16B addresses -> fully coalesced global_store_dwordx4.
    #pragma unroll
    for (int r = 0; r < 4; ++r) {
        const int g  = r * 256 + tid;   // 0..1023
        const int bl = g >> 4;          // local batch element
        const int q  = g & 15;          // float4 column within the row
        const int b  = b0 + bl;
        if (b < batch) {
            out4[(long)b * 16 + q] = s_table[s_idx[bl] * 16 + q];
        }
    }
}

extern "C" void kernel_launch(void* const* d_in, const int* in_sizes, int n_in,
                              void* d_out, int out_size, void* d_ws, size_t ws_size,
                              hipStream_t stream) {
    const float* table    = (const float*)d_in[0];   // [64,64] float32
    const int*   idx_bits = (const int*)d_in[1];     // [batch,6] int32
    float4*      out4     = (float4*)d_out;          // [batch,64] float32 as float4

    const int batch  = in_sizes[1] / 6;
    const int blocks = (batch + B_PER_BLOCK - 1) / B_PER_BLOCK;

    spike_lut_kernel<<<blocks, 256, 0, stream>>>(table, idx_bits, out4, batch);
}

// Round 2
// 80.193 us; speedup vs baseline: 1.0063x; 1.0063x over previous
//
#include <hip/hip_runtime.h>

// out[b][j] = table_bits[idx(b)][j]; idx(b) = MSB-first pack of (idx_bits[b][k] > 0).
// Pure streaming problem: read 6 MiB idx_bits, write 64 MiB output.
// Harness fill rate on this chip: 6.15 TB/s (measured from re-poison dispatches)
// -> target ~12 us kernel time.

#define ROWS 256   // batch rows per block: 256 rows x 64 floats = 64 KB out/block

__global__ __launch_bounds__(256) void
spike_lut_kernel(const float* __restrict__ table,      // [64 rows][64 bits] float32
                 const int* __restrict__ idx_bits,     // [batch][6] int32
                 float4* __restrict__ out4,            // [batch][16] float4
                 int batch) {
    __shared__ float4 s_table[64 * 16];   // 16 KB full table
    __shared__ int    s_raw[ROWS * 6];    // 6 KB staged idx_bits
    __shared__ int    s_idx[ROWS];        // 1 KB packed indices

    const int  tid = threadIdx.x;
    const long b0  = (long)blockIdx.x * ROWS;
    const bool full = (b0 + ROWS) <= batch;   // uniform per block

    // Stage table: 1024 float4 across 256 threads, coalesced dwordx4 (L2-hot).
    const float4* t4 = (const float4*)table;
    #pragma unroll
    for (int r = 0; r < 4; ++r)
        s_table[r * 256 + tid] = t4[r * 256 + tid];

    // Stage idx_bits: 1536 ints, 6 fully-coalesced 1KB/wave loads.
    const int* src = idx_bits + b0 * 6;
    if (full) {
        #pragma unroll
        for (int r = 0; r < 6; ++r)
            s_raw[r * 256 + tid] = src[r * 256 + tid];
    } else {
        const long lim = ((long)batch - b0) * 6;
        #pragma unroll
        for (int r = 0; r < 6; ++r) {
            const int g = r * 256 + tid;
            s_raw[g] = (g < lim) ? src[g] : 0;
        }
    }
    __syncthreads();

    // Each thread packs its row's 6 bits (stride-6 LDS reads: 2-way alias = free).
    {
        const int* p = &s_raw[tid * 6];
        int idx = 0;
        #pragma unroll
        for (int k = 0; k < 6; ++k)
            idx = (idx << 1) | (p[k] > 0 ? 1 : 0);   // k=0 is MSB (weight 32)
        s_idx[tid] = idx;
    }
    __syncthreads();

    // Emit 256 rows x 16 float4 = 4096 float4/block; consecutive lanes hit
    // consecutive 16B addresses -> 1KB/wave global_store_dwordx4, fill-like.
    if (full) {
        #pragma unroll
        for (int it = 0; it < 16; ++it) {
            const int g  = it * 256 + tid;
            const int bl = g >> 4;
            const int q  = g & 15;
            out4[(b0 + bl) * 16 + q] = s_table[s_idx[bl] * 16 + q];
        }
    } else {
        #pragma unroll
        for (int it = 0; it < 16; ++it) {
            const int g  = it * 256 + tid;
            const int bl = g >> 4;
            const int q  = g & 15;
            if (b0 + bl < batch)
                out4[(b0 + bl) * 16 + q] = s_table[s_idx[bl] * 16 + q];
        }
    }
}

extern "C" void kernel_launch(void* const* d_in, const int* in_sizes, int n_in,
                              void* d_out, int out_size, void* d_ws, size_t ws_size,
                              hipStream_t stream) {
    const float* table    = (const float*)d_in[0];   // [64,64] float32
    const int*   idx_bits = (const int*)d_in[1];     // [batch,6] int32
    float4*      out4     = (float4*)d_out;

    const int batch  = in_sizes[1] / 6;
    const int blocks = (batch + ROWS - 1) / ROWS;

    spike_lut_kernel<<<blocks, 256, 0, stream>>>(table, idx_bits, out4, batch);
}